// Round 8
// baseline (191.209 us; speedup 1.0000x reference)
//
#include <hip/hip_runtime.h>
#include <math.h>

// Problem constants
#define S_N 16
#define D_N 256
#define H_N 128
#define K_N 32
#define BT  32      // batch rows per workgroup
#define B_N 16384

typedef __attribute__((ext_vector_type(8))) short bf16x8;
typedef __attribute__((ext_vector_type(4))) float f32x4;

#define MFMA(a, b, c) __builtin_amdgcn_mfma_f32_16x16x32_bf16(a, b, c, 0, 0, 0)

static __device__ __forceinline__ unsigned short f2bf(float f) {
  union { float f; unsigned u; } v; v.f = f;
  unsigned r = v.u + 0x7FFFu + ((v.u >> 16) & 1u);  // RNE
  return (unsigned short)(r >> 16);
}

// ---------------- merged pre-pass ----------------
__global__ __launch_bounds__(256)
void lsi_prep(const float* __restrict__ W1, const float* __restrict__ W2,
              const float* __restrict__ Wc1, const float* __restrict__ b2,
              const float* __restrict__ bc1,
              unsigned short* __restrict__ W1t,
              unsigned short* __restrict__ W2t,
              unsigned short* __restrict__ Wft,
              float* __restrict__ bcf)
{
  const int bid = blockIdx.x;
  if (bid < 1024) {
    __shared__ float t[32][33];
    const float* src; unsigned short* dst; int R, C, r0, c0;
    if (bid < 512) {
      int s = bid >> 5, tt = bid & 31;
      R = 256; C = 128; r0 = (tt >> 2) * 32; c0 = (tt & 3) * 32;
      src = W1 + (size_t)s * 256 * 128; dst = W1t + (size_t)s * 128 * 256;
    } else {
      int s = (bid - 512) >> 5, tt = (bid - 512) & 31;
      R = 128; C = 256; r0 = (tt >> 3) * 32; c0 = (tt & 7) * 32;
      src = W2 + (size_t)s * 128 * 256; dst = W2t + (size_t)s * 256 * 128;
    }
    int li = threadIdx.x >> 5, lj = threadIdx.x & 31;
    #pragma unroll
    for (int i = 0; i < 4; ++i)
      t[li + i * 8][lj] = src[(size_t)(r0 + li + i * 8) * C + c0 + lj];
    __syncthreads();
    #pragma unroll
    for (int i = 0; i < 4; ++i)
      dst[(size_t)(c0 + li + i * 8) * R + r0 + lj] = f2bf(t[lj][li + i * 8]);
    return;
  }
  // wfuse: 128 blocks, 8 per source (16 hh rows each)
  const int q  = bid - 1024;
  const int s  = q >> 3, hb = q & 7;
  const int t  = threadIdx.x;
  const int hh = hb * 16 + (t >> 4);
  const int kb = (t & 15) * 2;
  const float* w2r = W2 + ((size_t)s * H_N + hh) * D_N;
  const float* wc1 = Wc1 + (size_t)s * D_N * K_N;
  float a0 = 0.f, a1 = 0.f;
  for (int d = 0; d < D_N; ++d) {
    float wv = w2r[d];
    a0 = fmaf(wv, wc1[d * K_N + kb], a0);
    a1 = fmaf(wv, wc1[d * K_N + kb + 1], a1);
  }
  Wft[((size_t)s * K_N + kb) * H_N + hh]     = f2bf(a0);
  Wft[((size_t)s * K_N + kb + 1) * H_N + hh] = f2bf(a1);
  if (hb == 0 && t < K_N) {
    float a = bc1[s * K_N + t];
    for (int d = 0; d < D_N; ++d)
      a = fmaf(b2[s * D_N + d], wc1[d * K_N + t], a);
    bcf[s * K_N + t] = a;
  }
}

// ---------------- fused main kernel ----------------
// 256-THREAD blocks (4 waves = 1 wave/SIMD each): co-residency quantum is
// 1 wave/SIMD, so 3-4 blocks/CU fit at <=170/<=128 unified regs (R7 lesson:
// 512-thr blocks need total<=128 for 2 blocks -> impossible without spills).
// SPLIT=1: grid 1024, bid=(rowgrp=bid&511, half=bid>>9), 8 sources per block,
//          partial out/wsum. SPLIT=0: grid 512, 16 sources, final out.
// Per source (2 barriers):
//   P1: GEMM1(s): wave w -> h-cols [32w,32w+32) x 32 rows + fold(s-1) -> h_lds
//   barA
//   P2: waves 0-1: GEMM3' rows [16w,16w+16) full 32 ch-cols -> in-wave reduce
//       -> cw_lds/wsum_lds;  all waves: GEMM2: wave w -> d-cols [64w,64w+64)
//   barB
template<int SPLIT>
__global__ __launch_bounds__(256, 4)
void lsi_main(const float* __restrict__ x,
              const float* __restrict__ b1,
              const float* __restrict__ b2,
              const float* __restrict__ Wc2,
              const float* __restrict__ bc2,
              const float* __restrict__ lam,
              const unsigned short* __restrict__ W1t,
              const unsigned short* __restrict__ W2t,
              const unsigned short* __restrict__ Wft,
              const float* __restrict__ bcf,
              float* __restrict__ outp,
              float* __restrict__ pwsum)
{
  __shared__ unsigned short x_lds[BT * D_N];   // 16 KB, swizzled
  __shared__ unsigned short h_lds[BT * H_N];   // 8 KB, swizzled
  __shared__ float cw_lds[BT];
  __shared__ float wsum_lds[BT];

  const int tid = threadIdx.x;
  const int w   = tid >> 6;       // wave 0..3
  const int l   = tid & 63;       // lane
  const int rA  = l & 15;
  const int g   = l >> 4;         // k-group 0..3
  const int k8  = g * 8;

  int rb, half, s0, ns;
  if (SPLIT) { rb = blockIdx.x & 511; half = blockIdx.x >> 9; s0 = half * 8; ns = 8; }
  else       { rb = blockIdx.x;       half = 0;               s0 = 0;        ns = 16; }
  const int b0 = rb * BT;

  // ---- stage x tile into LDS as bf16 (swizzled) ----
  {
    int row = tid >> 3;                 // 0..31
    int c0  = (tid & 7) * 32;           // 8 threads per row
    const float* xr = x + (size_t)(b0 + row) * D_N + c0;
    #pragma unroll
    for (int cc = 0; cc < 4; ++cc) {
      float4 f0 = *(const float4*)(xr + cc * 8);
      float4 f1 = *(const float4*)(xr + cc * 8 + 4);
      bf16x8 u;
      u[0] = f2bf(f0.x); u[1] = f2bf(f0.y); u[2] = f2bf(f0.z); u[3] = f2bf(f0.w);
      u[4] = f2bf(f1.x); u[5] = f2bf(f1.y); u[6] = f2bf(f1.z); u[7] = f2bf(f1.w);
      unsigned off = (unsigned)(row * 512 + (c0 + cc * 8) * 2) ^ (unsigned)((row & 7) << 4);
      *(bf16x8*)((char*)x_lds + off) = u;
    }
  }
  if (tid < BT) wsum_lds[tid] = 0.f;

  f32x4 out_acc[4][2];   // [ct][rt] persistent (wave cols 64w..64w+64)
  f32x4 acc2[4][2];      // [ct][rt] outs(s), folded one source later
  #pragma unroll
  for (int a = 0; a < 4; ++a)
    #pragma unroll
    for (int b = 0; b < 2; ++b)
      out_acc[a][b] = (f32x4){0.f, 0.f, 0.f, 0.f};

  __syncthreads();

  for (int si = 0; si < ns; ++si) {
    const int s = s0 + si;

    // ---------- P1: GEMM1(s) + fold(s-1) ----------
    f32x4 acc1[2][2];    // [ct][rt], h-cols 32w + 16ct + rA
    #pragma unroll
    for (int a = 0; a < 2; ++a)
      #pragma unroll
      for (int b = 0; b < 2; ++b)
        acc1[a][b] = (f32x4){0.f, 0.f, 0.f, 0.f};
    {
      const unsigned short* B1 = W1t + ((size_t)s * H_N + w * 32 + rA) * D_N + k8;
      #pragma unroll
      for (int ks = 0; ks < 8; ++ks) {
        bf16x8 bf0 = *(const bf16x8*)(B1 + ks * 32);
        bf16x8 bf1 = *(const bf16x8*)(B1 + 16 * D_N + ks * 32);
        #pragma unroll
        for (int rt = 0; rt < 2; ++rt) {
          int row = rt * 16 + rA;
          unsigned off = (unsigned)(row * 512 + (ks * 32 + k8) * 2) ^ (unsigned)((row & 7) << 4);
          bf16x8 afr = *(const bf16x8*)((const char*)x_lds + off);
          acc1[0][rt] = MFMA(afr, bf0, acc1[0][rt]);
          acc1[1][rt] = MFMA(afr, bf1, acc1[1][rt]);
        }
      }
    }
    if (si > 0) {   // fold source s-1 (VALU, overlaps GEMM1 MFMA)
      #pragma unroll
      for (int rt = 0; rt < 2; ++rt) {
        f32x4 c4 = *(const f32x4*)&cw_lds[rt * 16 + g * 4];
        #pragma unroll
        for (int ct = 0; ct < 4; ++ct)
          #pragma unroll
          for (int i = 0; i < 4; ++i)
            out_acc[ct][rt][i] += c4[i] * acc2[ct][rt][i];
      }
    }
    // write h = relu(acc1 + b1) -> LDS (bf16, swizzled)
    {
      const float bv0 = b1[s * H_N + w * 32 + rA];
      const float bv1 = b1[s * H_N + w * 32 + 16 + rA];
      #pragma unroll
      for (int ct = 0; ct < 2; ++ct)
        #pragma unroll
        for (int rt = 0; rt < 2; ++rt)
          #pragma unroll
          for (int i = 0; i < 4; ++i) {
            float v = fmaxf(acc1[ct][rt][i] + (ct ? bv1 : bv0), 0.f);
            int row = rt * 16 + g * 4 + i;
            unsigned off = (unsigned)(row * 256 + (w * 32 + ct * 16 + rA) * 2) ^ (unsigned)((row & 7) << 4);
            *(unsigned short*)((char*)h_lds + off) = f2bf(v);
          }
    }
    __syncthreads();   // barA: h ready

    // ---------- P2a: waves 0-1: GEMM3' (16 rows, full 32 ch-cols) ----------
    if (w < 2) {
      f32x4 acc3[2];
      acc3[0] = (f32x4){0.f, 0.f, 0.f, 0.f};
      acc3[1] = (f32x4){0.f, 0.f, 0.f, 0.f};
      const unsigned short* Bf = Wft + ((size_t)s * K_N + rA) * H_N + k8;
      #pragma unroll
      for (int ks = 0; ks < 4; ++ks) {
        int row = w * 16 + rA;
        unsigned off = (unsigned)(row * 256 + (ks * 32 + k8) * 2) ^ (unsigned)((row & 7) << 4);
        bf16x8 afr = *(const bf16x8*)((const char*)h_lds + off);
        acc3[0] = MFMA(afr, *(const bf16x8*)(Bf + ks * 32), acc3[0]);
        acc3[1] = MFMA(afr, *(const bf16x8*)(Bf + 16 * H_N + ks * 32), acc3[1]);
      }
      const float bcf0 = bcf[s * K_N + rA],      bcf1 = bcf[s * K_N + 16 + rA];
      const float wc20 = Wc2[s * K_N + rA],      wc21 = Wc2[s * K_N + 16 + rA];
      float pz[4];
      #pragma unroll
      for (int i = 0; i < 4; ++i)
        pz[i] = fmaxf(acc3[0][i] + bcf0, 0.f) * wc20 +
                fmaxf(acc3[1][i] + bcf1, 0.f) * wc21;
      #pragma unroll
      for (int m = 1; m < 16; m <<= 1)
        #pragma unroll
        for (int i = 0; i < 4; ++i)
          pz[i] += __shfl_xor(pz[i], m);
      if (rA == 0) {
        const float lam_s = lam[s], bc2_s = bc2[s];
        #pragma unroll
        for (int i = 0; i < 4; ++i) {
          float cv = lam_s / (1.f + __expf(-(pz[i] + bc2_s)));
          cw_lds[w * 16 + g * 4 + i] = cv;
          wsum_lds[w * 16 + g * 4 + i] += cv;
        }
      }
    }

    // ---------- P2b: GEMM2(s) -> acc2 (all waves, d-cols 64w..64w+64) ----------
    #pragma unroll
    for (int a = 0; a < 4; ++a)
      #pragma unroll
      for (int b = 0; b < 2; ++b)
        acc2[a][b] = (f32x4){0.f, 0.f, 0.f, 0.f};
    {
      const unsigned short* B2 = W2t + ((size_t)s * D_N + w * 64 + rA) * H_N + k8;
      #pragma unroll
      for (int ks = 0; ks < 4; ++ks) {
        bf16x8 afr[2];
        #pragma unroll
        for (int rt = 0; rt < 2; ++rt) {
          int row = rt * 16 + rA;
          unsigned off = (unsigned)(row * 256 + (ks * 32 + k8) * 2) ^ (unsigned)((row & 7) << 4);
          afr[rt] = *(const bf16x8*)((const char*)h_lds + off);
        }
        #pragma unroll
        for (int ct = 0; ct < 4; ++ct) {
          bf16x8 bfr = *(const bf16x8*)(B2 + ct * 16 * H_N + ks * 32);
          #pragma unroll
          for (int rt = 0; rt < 2; ++rt)
            acc2[ct][rt] = MFMA(afr[rt], bfr, acc2[ct][rt]);
        }
      }
    }
    {
      #pragma unroll
      for (int ct = 0; ct < 4; ++ct) {
        float b2v = b2[s * D_N + w * 64 + ct * 16 + rA];
        #pragma unroll
        for (int rt = 0; rt < 2; ++rt)
          #pragma unroll
          for (int i = 0; i < 4; ++i)
            acc2[ct][rt][i] += b2v;
      }
    }
    __syncthreads();   // barB: h free for s+1, cw(s) published
  }

  // ---------- epilogue: fold last source, store ----------
  #pragma unroll
  for (int rt = 0; rt < 2; ++rt) {
    f32x4 c4 = *(const f32x4*)&cw_lds[rt * 16 + g * 4];
    #pragma unroll
    for (int ct = 0; ct < 4; ++ct)
      #pragma unroll
      for (int i = 0; i < 4; ++i)
        out_acc[ct][rt][i] += c4[i] * acc2[ct][rt][i];
  }
  if (SPLIT) {
    float* po = outp + (size_t)half * B_N * D_N;
    #pragma unroll
    for (int rt = 0; rt < 2; ++rt)
      #pragma unroll
      for (int i = 0; i < 4; ++i) {
        int row = rt * 16 + g * 4 + i;
        #pragma unroll
        for (int ct = 0; ct < 4; ++ct)
          po[(size_t)(b0 + row) * D_N + w * 64 + ct * 16 + rA] = out_acc[ct][rt][i];
      }
    if (tid < BT) pwsum[half * B_N + b0 + tid] = wsum_lds[tid];
  } else {
    #pragma unroll
    for (int rt = 0; rt < 2; ++rt) {
      f32x4 w4 = *(const f32x4*)&wsum_lds[rt * 16 + g * 4];
      #pragma unroll
      for (int i = 0; i < 4; ++i) {
        int row = rt * 16 + g * 4 + i;
        float winv = 1.f / (w4[i] + 1e-6f);
        #pragma unroll
        for (int ct = 0; ct < 4; ++ct)
          outp[(size_t)(b0 + row) * D_N + w * 64 + ct * 16 + rA] = out_acc[ct][rt][i] * winv;
      }
    }
  }
}

// ---------------- combine (SPLIT path) ----------------
__global__ __launch_bounds__(256)
void lsi_combine(const float* __restrict__ pout, const float* __restrict__ pwsum,
                 float* __restrict__ out)
{
  size_t i4 = ((size_t)blockIdx.x * 256 + threadIdx.x) * 4;
  int row = (int)(i4 >> 8);   // D_N = 256
  f32x4 a = *(const f32x4*)(pout + i4);
  f32x4 b = *(const f32x4*)(pout + (size_t)B_N * D_N + i4);
  float ws = pwsum[row] + pwsum[B_N + row];
  float inv = 1.f / (ws + 1e-6f);
  f32x4 r;
  #pragma unroll
  for (int i = 0; i < 4; ++i) r[i] = (a[i] + b[i]) * inv;
  *(f32x4*)(out + i4) = r;
}

extern "C" void kernel_launch(void* const* d_in, const int* in_sizes, int n_in,
                              void* d_out, int out_size, void* d_ws, size_t ws_size,
                              hipStream_t stream) {
  const float* x   = (const float*)d_in[0];
  const float* W1  = (const float*)d_in[1];
  const float* b1  = (const float*)d_in[2];
  const float* W2  = (const float*)d_in[3];
  const float* b2  = (const float*)d_in[4];
  const float* Wc1 = (const float*)d_in[5];
  const float* bc1 = (const float*)d_in[6];
  const float* Wc2 = (const float*)d_in[7];
  const float* bc2 = (const float*)d_in[8];
  const float* lam = (const float*)d_in[9];
  float* out = (float*)d_out;

  // ws layout: W1t 1MB | W2t 1MB | Wft 128KB | bcf 2KB | pwsum 128KB | pout 32MB
  unsigned short* W1t = (unsigned short*)d_ws;
  unsigned short* W2t = W1t + (size_t)S_N * H_N * D_N;
  unsigned short* Wft = W2t + (size_t)S_N * D_N * H_N;
  float* bcf   = (float*)(Wft + (size_t)S_N * K_N * H_N);
  float* pwsum = bcf + S_N * K_N;
  float* pout  = pwsum + 2 * B_N;
  size_t need = (size_t)((char*)(pout + (size_t)2 * B_N * D_N) - (char*)d_ws);

  lsi_prep<<<dim3(1152), dim3(256), 0, stream>>>(W1, W2, Wc1, b2, bc1,
                                                 W1t, W2t, Wft, bcf);
  if (ws_size >= need) {
    lsi_main<1><<<dim3(1024), dim3(256), 0, stream>>>(x, b1, b2, Wc2, bc2, lam,
                                                      W1t, W2t, Wft, bcf, pout, pwsum);
    lsi_combine<<<dim3((B_N * D_N) / 1024), dim3(256), 0, stream>>>(pout, pwsum, out);
  } else {
    lsi_main<0><<<dim3(512), dim3(256), 0, stream>>>(x, b1, b2, Wc2, bc2, lam,
                                                     W1t, W2t, Wft, bcf, out, nullptr);
  }
}

// Round 9
// 123.900 us; speedup vs baseline: 1.5432x; 1.5432x over previous
//
#include <hip/hip_runtime.h>
#include <math.h>

// Problem constants
#define S_N 16
#define D_N 256
#define H_N 128
#define K_N 32
#define BT  64      // batch rows per workgroup
#define B_N 16384

typedef __attribute__((ext_vector_type(8))) short bf16x8;
typedef __attribute__((ext_vector_type(4))) float f32x4;

#define MFMA(a, b, c) __builtin_amdgcn_mfma_f32_16x16x32_bf16(a, b, c, 0, 0, 0)

static __device__ __forceinline__ unsigned short f2bf(float f) {
  union { float f; unsigned u; } v; v.f = f;
  unsigned r = v.u + 0x7FFFu + ((v.u >> 16) & 1u);  // RNE
  return (unsigned short)(r >> 16);
}

// ---------------- merged pre-pass ----------------
__global__ __launch_bounds__(256)
void lsi_prep(const float* __restrict__ W1, const float* __restrict__ W2,
              const float* __restrict__ Wc1, const float* __restrict__ b2,
              const float* __restrict__ bc1,
              unsigned short* __restrict__ W1t,
              unsigned short* __restrict__ W2t,
              unsigned short* __restrict__ Wft,
              float* __restrict__ bcf)
{
  const int bid = blockIdx.x;
  if (bid < 1024) {
    __shared__ float t[32][33];
    const float* src; unsigned short* dst; int R, C, r0, c0;
    if (bid < 512) {
      int s = bid >> 5, tt = bid & 31;
      R = 256; C = 128; r0 = (tt >> 2) * 32; c0 = (tt & 3) * 32;
      src = W1 + (size_t)s * 256 * 128; dst = W1t + (size_t)s * 128 * 256;
    } else {
      int s = (bid - 512) >> 5, tt = (bid - 512) & 31;
      R = 128; C = 256; r0 = (tt >> 3) * 32; c0 = (tt & 7) * 32;
      src = W2 + (size_t)s * 128 * 256; dst = W2t + (size_t)s * 256 * 128;
    }
    int li = threadIdx.x >> 5, lj = threadIdx.x & 31;
    #pragma unroll
    for (int i = 0; i < 4; ++i)
      t[li + i * 8][lj] = src[(size_t)(r0 + li + i * 8) * C + c0 + lj];
    __syncthreads();
    #pragma unroll
    for (int i = 0; i < 4; ++i)
      dst[(size_t)(c0 + li + i * 8) * R + r0 + lj] = f2bf(t[lj][li + i * 8]);
    return;
  }
  // wfuse: 128 blocks, 8 per source (16 hh rows each)
  const int q  = bid - 1024;
  const int s  = q >> 3, hb = q & 7;
  const int t  = threadIdx.x;
  const int hh = hb * 16 + (t >> 4);
  const int kb = (t & 15) * 2;
  const float* w2r = W2 + ((size_t)s * H_N + hh) * D_N;
  const float* wc1 = Wc1 + (size_t)s * D_N * K_N;
  float a0 = 0.f, a1 = 0.f;
  for (int d = 0; d < D_N; ++d) {
    float wv = w2r[d];
    a0 = fmaf(wv, wc1[d * K_N + kb], a0);
    a1 = fmaf(wv, wc1[d * K_N + kb + 1], a1);
  }
  Wft[((size_t)s * K_N + kb) * H_N + hh]     = f2bf(a0);
  Wft[((size_t)s * K_N + kb + 1) * H_N + hh] = f2bf(a1);
  if (hb == 0 && t < K_N) {
    float a = bc1[s * K_N + t];
    for (int d = 0; d < D_N; ++d)
      a = fmaf(b2[s * D_N + d], wc1[d * K_N + t], a);
    bcf[s * K_N + t] = a;
  }
}

// ---------------- fused main kernel ----------------
// grid = 256, block = 512 (8 waves), 1 block/CU (occupancy pinned by
// out_acc+acc2 register state — R6/R8: any attempt to co-reside 2 blocks
// forces a VGPR/AGPR split that spills ~45-300MB).
// ONE barrier per source; double-buffered h; per phase(s):
//   fold(s-1) [VALU] ; conf(s) on waves 0-3 only (h.Wf, in-wave shfl
//   reduce -> cw_lds[s&1], no zp stage) ; GEMM2(s) -> acc2 [LDS+L2+MFMA] ;
//   GEMM1(s+1) -> h[(s+1)&1] [LDS+L2+MFMA] ; __syncthreads()
// Waves 4-7 skip conf -> wave-heterogeneous phases (pipe mixing).
__global__ __launch_bounds__(512, 2)
void lsi_main(const float* __restrict__ x,
              const float* __restrict__ b1,
              const float* __restrict__ b2,
              const float* __restrict__ Wc2,
              const float* __restrict__ bc2,
              const float* __restrict__ lam,
              const unsigned short* __restrict__ W1t,
              const unsigned short* __restrict__ W2t,
              const unsigned short* __restrict__ Wft,
              const float* __restrict__ bcf,
              float* __restrict__ out)
{
  __shared__ unsigned short x_lds[BT * D_N];      // 32 KB, swizzled
  __shared__ unsigned short h_lds[2][BT * H_N];   // 2 x 16 KB, swizzled
  __shared__ float cw_lds[2][BT];
  __shared__ float wsum_lds[BT];

  const int tid = threadIdx.x;
  const int w   = tid >> 6;       // wave 0..7
  const int l   = tid & 63;       // lane
  const int rA  = l & 15;
  const int g   = l >> 4;         // k-group 0..3
  const int k8  = g * 8;
  const int b0  = blockIdx.x * BT;

  // ---- stage x tile into LDS as bf16 (swizzled) ----
  {
    int row = tid >> 3;                 // 0..63
    int c0  = (tid & 7) * 32;           // 8 threads per row
    const float* xr = x + (size_t)(b0 + row) * D_N + c0;
    #pragma unroll
    for (int cc = 0; cc < 4; ++cc) {
      float4 f0 = *(const float4*)(xr + cc * 8);
      float4 f1 = *(const float4*)(xr + cc * 8 + 4);
      bf16x8 u;
      u[0] = f2bf(f0.x); u[1] = f2bf(f0.y); u[2] = f2bf(f0.z); u[3] = f2bf(f0.w);
      u[4] = f2bf(f1.x); u[5] = f2bf(f1.y); u[6] = f2bf(f1.z); u[7] = f2bf(f1.w);
      unsigned off = (unsigned)(row * 512 + (c0 + cc * 8) * 2) ^ (unsigned)((row & 7) << 4);
      *(bf16x8*)((char*)x_lds + off) = u;
    }
  }
  if (tid < BT) wsum_lds[tid] = 0.f;

  f32x4 out_acc[2][4];   // [ct][rt] persistent
  f32x4 acc2[2][4];      // [ct][rt] outs(s), folded one source later
  #pragma unroll
  for (int a = 0; a < 2; ++a)
    #pragma unroll
    for (int b = 0; b < 4; ++b)
      out_acc[a][b] = (f32x4){0.f, 0.f, 0.f, 0.f};

  // GEMM1 for source s -> given h buffer (col-split: wave w -> cols 16w..16w+16)
  auto do_gemm1 = [&](int s, unsigned short* hw) {
    f32x4 acc1[4];
    #pragma unroll
    for (int rt = 0; rt < 4; ++rt) acc1[rt] = (f32x4){0.f, 0.f, 0.f, 0.f};
    const unsigned short* B1 = W1t + ((size_t)s * H_N + w * 16 + rA) * D_N + k8;
    #pragma unroll
    for (int ks = 0; ks < 8; ++ks) {
      bf16x8 bfr = *(const bf16x8*)(B1 + ks * 32);
      #pragma unroll
      for (int rt = 0; rt < 4; ++rt) {
        int row = rt * 16 + rA;
        unsigned off = (unsigned)(row * 512 + (ks * 32 + k8) * 2) ^ (unsigned)((row & 7) << 4);
        bf16x8 afr = *(const bf16x8*)((const char*)x_lds + off);
        acc1[rt] = MFMA(afr, bfr, acc1[rt]);
      }
    }
    const float b1v = b1[s * H_N + w * 16 + rA];
    #pragma unroll
    for (int rt = 0; rt < 4; ++rt)
      #pragma unroll
      for (int i = 0; i < 4; ++i) {
        float v = fmaxf(acc1[rt][i] + b1v, 0.f);
        int row = rt * 16 + g * 4 + i;
        unsigned off = (unsigned)(row * 256 + (w * 16 + rA) * 2) ^ (unsigned)((row & 7) << 4);
        *(unsigned short*)((char*)hw + off) = f2bf(v);
      }
  };

  __syncthreads();             // x staged
  do_gemm1(0, h_lds[0]);       // prologue
  __syncthreads();             // h(0) ready

  for (int s = 0; s < S_N; ++s) {
    const unsigned short* hr = (const unsigned short*)h_lds[s & 1];

    // ---- fold(s-1): VALU, overlaps following MFMA phases of other waves ----
    if (s > 0) {
      #pragma unroll
      for (int rt = 0; rt < 4; ++rt) {
        f32x4 c4 = *(const f32x4*)&cw_lds[(s + 1) & 1][rt * 16 + g * 4];
        #pragma unroll
        for (int i = 0; i < 4; ++i) {
          out_acc[0][rt][i] += c4[i] * acc2[0][rt][i];
          out_acc[1][rt][i] += c4[i] * acc2[1][rt][i];
        }
      }
    }

    // ---- conf(s): waves 0-3 only; wave w -> rows [16w,16w+16), all 32 k ----
    if (w < 4) {
      f32x4 acc3[2];
      acc3[0] = (f32x4){0.f, 0.f, 0.f, 0.f};
      acc3[1] = (f32x4){0.f, 0.f, 0.f, 0.f};
      const unsigned short* Bf = Wft + ((size_t)s * K_N + rA) * H_N + k8;
      #pragma unroll
      for (int ks = 0; ks < 4; ++ks) {
        int row = w * 16 + rA;
        unsigned off = (unsigned)(row * 256 + (ks * 32 + k8) * 2) ^ (unsigned)((row & 7) << 4);
        bf16x8 afr = *(const bf16x8*)((const char*)hr + off);
        acc3[0] = MFMA(afr, *(const bf16x8*)(Bf + ks * 32), acc3[0]);
        acc3[1] = MFMA(afr, *(const bf16x8*)(Bf + 16 * H_N + ks * 32), acc3[1]);
      }
      const float bcf0 = bcf[s * K_N + rA],  bcf1 = bcf[s * K_N + 16 + rA];
      const float wc20 = Wc2[s * K_N + rA],  wc21 = Wc2[s * K_N + 16 + rA];
      float pz[4];
      #pragma unroll
      for (int i = 0; i < 4; ++i)
        pz[i] = fmaxf(acc3[0][i] + bcf0, 0.f) * wc20 +
                fmaxf(acc3[1][i] + bcf1, 0.f) * wc21;
      #pragma unroll
      for (int m = 1; m < 16; m <<= 1)
        #pragma unroll
        for (int i = 0; i < 4; ++i)
          pz[i] += __shfl_xor(pz[i], m);
      if (rA == 0) {
        const float lam_s = lam[s], bc2_s = bc2[s];
        #pragma unroll
        for (int i = 0; i < 4; ++i) {
          float cv = lam_s / (1.f + __expf(-(pz[i] + bc2_s)));
          cw_lds[s & 1][w * 16 + g * 4 + i] = cv;
          wsum_lds[w * 16 + g * 4 + i] += cv;
        }
      }
    }

    // ---- GEMM2(s) -> acc2 (all waves; wave w -> d-cols [32w,32w+32)) ----
    #pragma unroll
    for (int a = 0; a < 2; ++a)
      #pragma unroll
      for (int b = 0; b < 4; ++b)
        acc2[a][b] = (f32x4){0.f, 0.f, 0.f, 0.f};
    {
      const unsigned short* B2 = W2t + ((size_t)s * D_N + w * 32 + rA) * H_N + k8;
      #pragma unroll
      for (int ks = 0; ks < 4; ++ks) {
        bf16x8 afr[4];
        #pragma unroll
        for (int rt = 0; rt < 4; ++rt) {
          int row = rt * 16 + rA;
          unsigned off = (unsigned)(row * 256 + (ks * 32 + k8) * 2) ^ (unsigned)((row & 7) << 4);
          afr[rt] = *(const bf16x8*)((const char*)hr + off);
        }
        #pragma unroll
        for (int ct = 0; ct < 2; ++ct) {
          bf16x8 bfr = *(const bf16x8*)(B2 + ct * 16 * H_N + ks * 32);
          #pragma unroll
          for (int rt = 0; rt < 4; ++rt)
            acc2[ct][rt] = MFMA(afr[rt], bfr, acc2[ct][rt]);
        }
      }
      float b2v0 = b2[s * D_N + w * 32 + rA];
      float b2v1 = b2[s * D_N + w * 32 + 16 + rA];
      #pragma unroll
      for (int rt = 0; rt < 4; ++rt)
        #pragma unroll
        for (int i = 0; i < 4; ++i) {
          acc2[0][rt][i] += b2v0;
          acc2[1][rt][i] += b2v1;
        }
    }

    // ---- GEMM1(s+1) -> other h buffer ----
    if (s + 1 < S_N) do_gemm1(s + 1, h_lds[(s + 1) & 1]);

    __syncthreads();   // single barrier per source
  }

  // ---------- epilogue: fold s=15, normalize, store ----------
  #pragma unroll
  for (int rt = 0; rt < 4; ++rt) {
    f32x4 c4 = *(const f32x4*)&cw_lds[(S_N - 1) & 1][rt * 16 + g * 4];
    #pragma unroll
    for (int i = 0; i < 4; ++i) {
      out_acc[0][rt][i] += c4[i] * acc2[0][rt][i];
      out_acc[1][rt][i] += c4[i] * acc2[1][rt][i];
    }
  }
  #pragma unroll
  for (int rt = 0; rt < 4; ++rt) {
    f32x4 w4 = *(const f32x4*)&wsum_lds[rt * 16 + g * 4];
    #pragma unroll
    for (int i = 0; i < 4; ++i) {
      int row = rt * 16 + g * 4 + i;
      float winv = 1.f / (w4[i] + 1e-6f);
      out[(size_t)(b0 + row) * D_N + w * 32 + rA]      = out_acc[0][rt][i] * winv;
      out[(size_t)(b0 + row) * D_N + w * 32 + 16 + rA] = out_acc[1][rt][i] * winv;
    }
  }
}

extern "C" void kernel_launch(void* const* d_in, const int* in_sizes, int n_in,
                              void* d_out, int out_size, void* d_ws, size_t ws_size,
                              hipStream_t stream) {
  const float* x   = (const float*)d_in[0];
  const float* W1  = (const float*)d_in[1];
  const float* b1  = (const float*)d_in[2];
  const float* W2  = (const float*)d_in[3];
  const float* b2  = (const float*)d_in[4];
  const float* Wc1 = (const float*)d_in[5];
  const float* bc1 = (const float*)d_in[6];
  const float* Wc2 = (const float*)d_in[7];
  const float* bc2 = (const float*)d_in[8];
  const float* lam = (const float*)d_in[9];
  float* out = (float*)d_out;

  // ws: W1t 1MB | W2t 1MB | Wft 128KB | bcf 2KB
  unsigned short* W1t = (unsigned short*)d_ws;
  unsigned short* W2t = W1t + (size_t)S_N * H_N * D_N;
  unsigned short* Wft = W2t + (size_t)S_N * D_N * H_N;
  float* bcf = (float*)(Wft + (size_t)S_N * K_N * H_N);

  lsi_prep<<<dim3(1152), dim3(256), 0, stream>>>(W1, W2, Wc1, b2, bc1,
                                                 W1t, W2t, Wft, bcf);
  lsi_main<<<dim3(B_N / BT), dim3(512), 0, stream>>>(x, b1, b2, Wc2, bc2, lam,
                                                     W1t, W2t, Wft, bcf, out);
}